// Round 1
// baseline (668.345 us; speedup 1.0000x reference)
//
#include <hip/hip_runtime.h>

typedef _Float16 f16;
typedef f16  f16x8 __attribute__((ext_vector_type(8)));
typedef f16  f16x4 __attribute__((ext_vector_type(4)));
typedef float f32x4 __attribute__((ext_vector_type(4)));

#define DIM_   2048
#define SEQ_   2048
#define BATCH_ 2
#define MROWS_ (BATCH_*SEQ_)   // 4096
#define HD_    64
#define KVCOLS_ 1024           // k (512) and v (512) concatenated

__device__ __forceinline__ f32x4 mfma16(f16x8 a, f16x8 b, f32x4 c) {
  return __builtin_amdgcn_mfma_f32_16x16x32_f16(a, b, c, 0, 0, 0);
}

// ---------------- reductions: sum |w| ----------------
__global__ __launch_bounds__(256)
void abssum_kernel(const float* __restrict__ w, int n, float* __restrict__ out) {
  float s = 0.f;
  for (int i = blockIdx.x * 256 + threadIdx.x; i < n; i += gridDim.x * 256)
    s += fabsf(w[i]);
  #pragma unroll
  for (int off = 32; off > 0; off >>= 1)
    s += __shfl_down(s, off, 64);
  __shared__ float red[4];
  int lane = threadIdx.x & 63, wv = threadIdx.x >> 6;
  if (lane == 0) red[wv] = s;
  __syncthreads();
  if (threadIdx.x == 0)
    atomicAdd(out, red[0] + red[1] + red[2] + red[3]);
}

// ---------------- ternarize to fp16 {-1,0,1} ----------------
__global__ __launch_bounds__(256)
void ternarize_kernel(const float* __restrict__ w, int n4,
                      const float* __restrict__ sum, float inv_n,
                      unsigned short* __restrict__ t) {
  float scale = fmaxf(sum[0] * inv_n, 1e-6f);
  float thr = 0.05f * scale;
  int stride = gridDim.x * 256;
  for (int i = blockIdx.x * 256 + threadIdx.x; i < n4; i += stride) {
    float4 v = *(const float4*)(w + (long)i * 4);
    ushort4 o;
    o.x = v.x > thr ? 0x3C00 : (v.x < -thr ? 0xBC00 : 0);
    o.y = v.y > thr ? 0x3C00 : (v.y < -thr ? 0xBC00 : 0);
    o.z = v.z > thr ? 0x3C00 : (v.z < -thr ? 0xBC00 : 0);
    o.w = v.w > thr ? 0x3C00 : (v.w < -thr ? 0xBC00 : 0);
    *(ushort4*)(t + (long)i * 4) = o;
  }
}

// ---------------- split x into fp16 hi + lo ----------------
__global__ __launch_bounds__(256)
void splitx_kernel(const float* __restrict__ x, int n4,
                   f16* __restrict__ hi, f16* __restrict__ lo) {
  int stride = gridDim.x * 256;
  for (int i = blockIdx.x * 256 + threadIdx.x; i < n4; i += stride) {
    float4 v = *(const float4*)(x + (long)i * 4);
    f16x4 h, l;
    h[0] = (f16)v.x; l[0] = (f16)(v.x - (float)h[0]);
    h[1] = (f16)v.y; l[1] = (f16)(v.y - (float)h[1]);
    h[2] = (f16)v.z; l[2] = (f16)(v.z - (float)h[2]);
    h[3] = (f16)v.w; l[3] = (f16)(v.w - (float)h[3]);
    *(f16x4*)(hi + (long)i * 4) = h;
    *(f16x4*)(lo + (long)i * 4) = l;
  }
}

// ---------------- NT GEMM: C[m,n] = sum_k A[m,k]*B[n,k], f32 out ----------------
// 128x128 tile, BK=32, 256 threads (4 waves, each 64x64 = 4x4 x 16x16 frags)
template<bool SPLIT>
__global__ __launch_bounds__(256)
void gemm_nt(const f16* __restrict__ Ah, const f16* __restrict__ Al,
             const f16* __restrict__ B, float* __restrict__ C,
             int M, int N, int K) {
  __shared__ __attribute__((aligned(16))) f16 sAh[128 * 32];
  __shared__ __attribute__((aligned(16))) f16 sB [128 * 32];
  __shared__ __attribute__((aligned(16))) f16 sAl[SPLIT ? 128 * 32 : 8];

  const int tid  = threadIdx.x;
  const int lane = tid & 63;
  const int wv   = tid >> 6;
  const int wr   = (wv >> 1) * 64;
  const int wc   = (wv & 1) * 64;
  const int brow = blockIdx.y * 128;
  const int bcol = blockIdx.x * 128;
  const int srow = tid >> 2;          // 0..63
  const int scol = (tid & 3) * 8;     // 0,8,16,24
  const int fr   = lane & 15;
  const int fko  = (lane >> 4) * 8;

  f32x4 acc[4][4] = {};

  const int nk = K >> 5;
  for (int kt = 0; kt < nk; ++kt) {
    const int k0 = kt * 32;
    f16x8 ga0 = *(const f16x8*)(Ah + (long)(brow + srow) * K + k0 + scol);
    f16x8 ga1 = *(const f16x8*)(Ah + (long)(brow + 64 + srow) * K + k0 + scol);
    f16x8 gb0 = *(const f16x8*)(B  + (long)(bcol + srow) * K + k0 + scol);
    f16x8 gb1 = *(const f16x8*)(B  + (long)(bcol + 64 + srow) * K + k0 + scol);
    f16x8 gl0, gl1;
    if constexpr (SPLIT) {
      gl0 = *(const f16x8*)(Al + (long)(brow + srow) * K + k0 + scol);
      gl1 = *(const f16x8*)(Al + (long)(brow + 64 + srow) * K + k0 + scol);
    }
    __syncthreads();
    *(f16x8*)(sAh + srow * 32 + scol)        = ga0;
    *(f16x8*)(sAh + (64 + srow) * 32 + scol) = ga1;
    *(f16x8*)(sB  + srow * 32 + scol)        = gb0;
    *(f16x8*)(sB  + (64 + srow) * 32 + scol) = gb1;
    if constexpr (SPLIT) {
      *(f16x8*)(sAl + srow * 32 + scol)        = gl0;
      *(f16x8*)(sAl + (64 + srow) * 32 + scol) = gl1;
    }
    __syncthreads();

    f16x8 bfr[4];
    #pragma unroll
    for (int ni = 0; ni < 4; ++ni)
      bfr[ni] = *(const f16x8*)(sB + (wc + ni * 16 + fr) * 32 + fko);
    #pragma unroll
    for (int mi = 0; mi < 4; ++mi) {
      f16x8 ah = *(const f16x8*)(sAh + (wr + mi * 16 + fr) * 32 + fko);
      #pragma unroll
      for (int ni = 0; ni < 4; ++ni)
        acc[mi][ni] = mfma16(ah, bfr[ni], acc[mi][ni]);
      if constexpr (SPLIT) {
        f16x8 al = *(const f16x8*)(sAl + (wr + mi * 16 + fr) * 32 + fko);
        #pragma unroll
        for (int ni = 0; ni < 4; ++ni)
          acc[mi][ni] = mfma16(al, bfr[ni], acc[mi][ni]);
      }
    }
  }

  const int fq = lane >> 4;
  #pragma unroll
  for (int mi = 0; mi < 4; ++mi)
    #pragma unroll
    for (int ni = 0; ni < 4; ++ni)
      #pragma unroll
      for (int r = 0; r < 4; ++r)
        C[(long)(brow + wr + mi * 16 + fq * 4 + r) * N + (bcol + wc + ni * 16 + fr)]
            = acc[mi][ni][r];
}

// ---------------- flash attention (causal, GQA 4:1) ----------------
// grid (qblk=32, h=32, b=2), 256 threads = 4 waves x 16 q-rows, D=64, KV block 64.
// Q,K f32 (split to fp16 hi/lo for f32-grade scores), V fp16-from-f32.
__global__ __launch_bounds__(256)
void attn_kernel(const float* __restrict__ Q,   // [4096][2048]
                 const float* __restrict__ KV,  // [4096][1024] (k | v)
                 f16* __restrict__ AO) {        // [4096][2048]
  const int qblk = blockIdx.x;
  const int h    = blockIdx.y;
  const int b    = blockIdx.z;
  const int kh   = h >> 2;
  const int tid  = threadIdx.x;
  const int lane = tid & 63;
  const int w    = tid >> 6;
  const int fr   = lane & 15;
  const int fq   = lane >> 4;

  __shared__ __attribute__((aligned(16))) f16 sKh[64 * 72];
  __shared__ __attribute__((aligned(16))) f16 sKl[64 * 72];
  __shared__ __attribute__((aligned(16))) f16 sVt[64 * 72];   // [d][kv], pad 72
  __shared__ __attribute__((aligned(16))) f16 sP[4][16 * 72];

  const int qrow0 = qblk * 64 + w * 16;
  const float* qbase = Q + (long)(b * SEQ_ + qrow0 + fr) * DIM_ + h * HD_;
  f16x8 qh[2], ql[2];
  #pragma unroll
  for (int ks = 0; ks < 2; ++ks) {
    const float* qp = qbase + ks * 32 + fq * 8;
    #pragma unroll
    for (int j = 0; j < 8; ++j) {
      float v = qp[j];
      f16 hv = (f16)v;
      qh[ks][j] = hv;
      ql[ks][j] = (f16)(v - (float)hv);
    }
  }

  float m_run[4], l_run[4];
  #pragma unroll
  for (int r = 0; r < 4; ++r) { m_run[r] = -1e30f; l_run[r] = 0.f; }
  f32x4 o_acc[4] = {};

  const int krow = tid >> 2;          // 0..63
  const int kcol = (tid & 3) * 16;    // 0,16,32,48
  const int vkv  = lane;              // 0..63 (each lane a different kv row)
  const int vd0  = (tid >> 6) * 4;    // 0,4,8,12
  f16* pw = sP[w];

  for (int kb = 0; kb <= qblk; ++kb) {
    const long kvg = (long)(b * SEQ_ + kb * 64);
    // K rows: 16 f32 per thread, coalesced
    float kf[16];
    const float* kp = KV + (kvg + krow) * KVCOLS_ + kh * HD_ + kcol;
    #pragma unroll
    for (int i = 0; i < 4; ++i) {
      float4 v = *(const float4*)(kp + i * 4);
      kf[i*4+0] = v.x; kf[i*4+1] = v.y; kf[i*4+2] = v.z; kf[i*4+3] = v.w;
    }
    // V: 16 f32 per thread (row vkv, 4 col-groups) for transpose-store
    float vf[16];
    const float* vp = KV + (kvg + vkv) * KVCOLS_ + 512 + kh * HD_ + vd0;
    #pragma unroll
    for (int i = 0; i < 4; ++i) {
      float4 v = *(const float4*)(vp + i * 16);
      vf[i*4+0] = v.x; vf[i*4+1] = v.y; vf[i*4+2] = v.z; vf[i*4+3] = v.w;
    }
    __syncthreads();
    {
      f16x8 h0, h1, l0, l1;
      #pragma unroll
      for (int j = 0; j < 8; ++j) {
        f16 a = (f16)kf[j];     h0[j] = a; l0[j] = (f16)(kf[j]     - (float)a);
        f16 c = (f16)kf[8+j];   h1[j] = c; l1[j] = (f16)(kf[8+j]   - (float)c);
      }
      *(f16x8*)(sKh + krow * 72 + kcol)     = h0;
      *(f16x8*)(sKh + krow * 72 + kcol + 8) = h1;
      *(f16x8*)(sKl + krow * 72 + kcol)     = l0;
      *(f16x8*)(sKl + krow * 72 + kcol + 8) = l1;
    }
    #pragma unroll
    for (int i = 0; i < 4; ++i)
      #pragma unroll
      for (int j = 0; j < 4; ++j)
        sVt[(vd0 + i * 16 + j) * 72 + vkv] = (f16)vf[i * 4 + j];
    __syncthreads();

    // S = Q K^T (hi/lo split: qh*kh + ql*kh + qh*kl)
    f32x4 s[4] = {};
    #pragma unroll
    for (int ks = 0; ks < 2; ++ks) {
      #pragma unroll
      for (int ni = 0; ni < 4; ++ni) {
        f16x8 khf = *(const f16x8*)(sKh + (ni * 16 + fr) * 72 + ks * 32 + fq * 8);
        f16x8 klf = *(const f16x8*)(sKl + (ni * 16 + fr) * 72 + ks * 32 + fq * 8);
        s[ni] = mfma16(qh[ks], khf, s[ni]);
        s[ni] = mfma16(ql[ks], khf, s[ni]);
        s[ni] = mfma16(qh[ks], klf, s[ni]);
      }
    }
    float sv[4][4];
    #pragma unroll
    for (int ni = 0; ni < 4; ++ni)
      #pragma unroll
      for (int r = 0; r < 4; ++r)
        sv[ni][r] = s[ni][r] * 0.125f;
    if (kb == qblk) {
      #pragma unroll
      for (int ni = 0; ni < 4; ++ni) {
        int kvp = ni * 16 + fr;
        #pragma unroll
        for (int r = 0; r < 4; ++r)
          if (kvp > w * 16 + fq * 4 + r) sv[ni][r] = -1e30f;
      }
    }
    // online softmax per q-row (row r lives in the 16-lane group fq)
    #pragma unroll
    for (int r = 0; r < 4; ++r) {
      float mb = fmaxf(fmaxf(sv[0][r], sv[1][r]), fmaxf(sv[2][r], sv[3][r]));
      #pragma unroll
      for (int off = 8; off > 0; off >>= 1)
        mb = fmaxf(mb, __shfl_xor(mb, off, 16));
      float mn = fmaxf(m_run[r], mb);
      float al = __expf(m_run[r] - mn);
      m_run[r] = mn;
      l_run[r] *= al;
      #pragma unroll
      for (int di = 0; di < 4; ++di) o_acc[di][r] *= al;
      float rs = 0.f;
      #pragma unroll
      for (int ni = 0; ni < 4; ++ni) {
        float p = __expf(sv[ni][r] - mn);
        rs += p;
        pw[(fq * 4 + r) * 72 + ni * 16 + fr] = (f16)p;
      }
      #pragma unroll
      for (int off = 8; off > 0; off >>= 1)
        rs += __shfl_xor(rs, off, 16);
      l_run[r] += rs;
    }
    // O += P V   (A = P[16 x 64] from LDS, B = Vt[d][kv])
    #pragma unroll
    for (int ks = 0; ks < 2; ++ks) {
      f16x8 pa = *(const f16x8*)(pw + fr * 72 + ks * 32 + fq * 8);
      #pragma unroll
      for (int di = 0; di < 4; ++di) {
        f16x8 vt = *(const f16x8*)(sVt + (di * 16 + fr) * 72 + ks * 32 + fq * 8);
        o_acc[di] = mfma16(pa, vt, o_acc[di]);
      }
    }
  }

  #pragma unroll
  for (int di = 0; di < 4; ++di)
    #pragma unroll
    for (int r = 0; r < 4; ++r) {
      float val = o_acc[di][r] / l_run[r];
      AO[(long)(b * SEQ_ + qrow0 + fq * 4 + r) * DIM_ + h * HD_ + di * 16 + fr] = (f16)val;
    }
}

// ---------------- launch ----------------
extern "C" void kernel_launch(void* const* d_in, const int* in_sizes, int n_in,
                              void* d_out, int out_size, void* d_ws, size_t ws_size,
                              hipStream_t stream) {
  const float* x  = (const float*)d_in[0];
  const float* wq = (const float*)d_in[1];
  const float* wk = (const float*)d_in[2];
  const float* wv = (const float*)d_in[3];
  const float* wo = (const float*)d_in[4];
  char* ws = (char*)d_ws;

  size_t off = 0;
  float* sums = (float*)ws;                 off = 256;
  f16* x_hi  = (f16*)(ws + off);            off += (size_t)MROWS_ * DIM_ * 2;
  f16* x_lo  = (f16*)(ws + off);            off += (size_t)MROWS_ * DIM_ * 2;
  f16* wq_t  = (f16*)(ws + off);            off += (size_t)DIM_ * DIM_ * 2;
  f16* wkv_t = (f16*)(ws + off);            off += (size_t)KVCOLS_ * DIM_ * 2;
  f16* wo_t  = (f16*)(ws + off);            off += (size_t)DIM_ * DIM_ * 2;
  float* q_f = (float*)(ws + off);          off += (size_t)MROWS_ * DIM_ * 4;
  float* kv_f= (float*)(ws + off);          off += (size_t)MROWS_ * KVCOLS_ * 4;
  f16* ao    = (f16*)(ws + off);            off += (size_t)MROWS_ * DIM_ * 2;

  hipMemsetAsync(sums, 0, 256, stream);  // atomics must start at 0 on every replay

  abssum_kernel<<<dim3(512), dim3(256), 0, stream>>>(wq, DIM_ * DIM_, sums + 0);
  abssum_kernel<<<dim3(256), dim3(256), 0, stream>>>(wk, 512 * DIM_, sums + 1);
  abssum_kernel<<<dim3(256), dim3(256), 0, stream>>>(wv, 512 * DIM_, sums + 2);
  abssum_kernel<<<dim3(512), dim3(256), 0, stream>>>(wo, DIM_ * DIM_, sums + 3);

  ternarize_kernel<<<dim3(512), dim3(256), 0, stream>>>(
      wq, DIM_ * DIM_ / 4, sums + 0, 1.f / (float)(DIM_ * DIM_), (unsigned short*)wq_t);
  ternarize_kernel<<<dim3(256), dim3(256), 0, stream>>>(
      wk, 512 * DIM_ / 4, sums + 1, 1.f / (float)(512 * DIM_), (unsigned short*)wkv_t);
  ternarize_kernel<<<dim3(256), dim3(256), 0, stream>>>(
      wv, 512 * DIM_ / 4, sums + 2, 1.f / (float)(512 * DIM_),
      (unsigned short*)(wkv_t + (size_t)512 * DIM_));
  ternarize_kernel<<<dim3(512), dim3(256), 0, stream>>>(
      wo, DIM_ * DIM_ / 4, sums + 3, 1.f / (float)(DIM_ * DIM_), (unsigned short*)wo_t);

  splitx_kernel<<<dim3(1024), dim3(256), 0, stream>>>(x, MROWS_ * DIM_ / 4, x_hi, x_lo);

  gemm_nt<true><<<dim3(DIM_ / 128, MROWS_ / 128), dim3(256), 0, stream>>>(
      x_hi, x_lo, wq_t, q_f, MROWS_, DIM_, DIM_);
  gemm_nt<true><<<dim3(KVCOLS_ / 128, MROWS_ / 128), dim3(256), 0, stream>>>(
      x_hi, x_lo, wkv_t, kv_f, MROWS_, KVCOLS_, DIM_);

  attn_kernel<<<dim3(SEQ_ / 64, 32, BATCH_), dim3(256), 0, stream>>>(q_f, kv_f, ao);

  gemm_nt<false><<<dim3(DIM_ / 128, MROWS_ / 128), dim3(256), 0, stream>>>(
      ao, ao, wo_t, (float*)d_out, MROWS_, DIM_, DIM_);
}

// Round 2
// 451.263 us; speedup vs baseline: 1.4811x; 1.4811x over previous
//
#include <hip/hip_runtime.h>

typedef _Float16 f16;
typedef f16  f16x8 __attribute__((ext_vector_type(8)));
typedef f16  f16x4 __attribute__((ext_vector_type(4)));
typedef float f32x4 __attribute__((ext_vector_type(4)));

#define DIM_   2048
#define SEQ_   2048
#define BATCH_ 2
#define MROWS_ (BATCH_*SEQ_)   // 4096
#define HD_    64
#define KVW_   512             // k (or v) projection width

__device__ __forceinline__ f32x4 mfma16(f16x8 a, f16x8 b, f32x4 c) {
  return __builtin_amdgcn_mfma_f32_16x16x32_f16(a, b, c, 0, 0, 0);
}

// ---------------- reductions: sum |w| ----------------
__global__ __launch_bounds__(256)
void abssum_kernel(const float* __restrict__ w, int n, float* __restrict__ out) {
  float s = 0.f;
  for (int i = blockIdx.x * 256 + threadIdx.x; i < n; i += gridDim.x * 256)
    s += fabsf(w[i]);
  #pragma unroll
  for (int off = 32; off > 0; off >>= 1)
    s += __shfl_down(s, off, 64);
  __shared__ float red[4];
  int lane = threadIdx.x & 63, wv = threadIdx.x >> 6;
  if (lane == 0) red[wv] = s;
  __syncthreads();
  if (threadIdx.x == 0)
    atomicAdd(out, red[0] + red[1] + red[2] + red[3]);
}

// ---------------- ternarize to fp16 {-1,0,1} ----------------
__global__ __launch_bounds__(256)
void ternarize_kernel(const float* __restrict__ w, int n4,
                      const float* __restrict__ sum, float inv_n,
                      unsigned short* __restrict__ t) {
  float scale = fmaxf(sum[0] * inv_n, 1e-6f);
  float thr = 0.05f * scale;
  int stride = gridDim.x * 256;
  for (int i = blockIdx.x * 256 + threadIdx.x; i < n4; i += stride) {
    float4 v = *(const float4*)(w + (long)i * 4);
    ushort4 o;
    o.x = v.x > thr ? 0x3C00 : (v.x < -thr ? 0xBC00 : 0);
    o.y = v.y > thr ? 0x3C00 : (v.y < -thr ? 0xBC00 : 0);
    o.z = v.z > thr ? 0x3C00 : (v.z < -thr ? 0xBC00 : 0);
    o.w = v.w > thr ? 0x3C00 : (v.w < -thr ? 0xBC00 : 0);
    *(ushort4*)(t + (long)i * 4) = o;
  }
}

// ---------------- split x into fp16 hi + lo ----------------
__global__ __launch_bounds__(256)
void splitx_kernel(const float* __restrict__ x, int n4,
                   f16* __restrict__ hi, f16* __restrict__ lo) {
  int stride = gridDim.x * 256;
  for (int i = blockIdx.x * 256 + threadIdx.x; i < n4; i += stride) {
    float4 v = *(const float4*)(x + (long)i * 4);
    f16x4 h, l;
    h[0] = (f16)v.x; l[0] = (f16)(v.x - (float)h[0]);
    h[1] = (f16)v.y; l[1] = (f16)(v.y - (float)h[1]);
    h[2] = (f16)v.z; l[2] = (f16)(v.z - (float)h[2]);
    h[3] = (f16)v.w; l[3] = (f16)(v.w - (float)h[3]);
    *(f16x4*)(hi + (long)i * 4) = h;
    *(f16x4*)(lo + (long)i * 4) = l;
  }
}

// ---------------- NT GEMM: C[m,n] = sum_k A[m,k]*B[n,k] ----------------
// 128x128 tile, BK=32, 256 threads (4 waves, each 64x64 = 4x4 x 16x16 frags)
// OUTMODE 0: f32 C.  1: f16 hi/lo pair (O1,O2).  2: kv mode (cols<512 -> khi/klo,
// cols>=512 -> V transposed f16 into OV laid out [b][kh][d=64][s=2048]).
template<bool SPLIT, int OUTMODE>
__global__ __launch_bounds__(256)
void gemm_nt(const f16* __restrict__ Ah, const f16* __restrict__ Al,
             const f16* __restrict__ B,
             float* __restrict__ C, f16* __restrict__ O1, f16* __restrict__ O2,
             f16* __restrict__ OV, int M, int N, int K) {
  __shared__ __attribute__((aligned(16))) f16 sAh[128 * 32];
  __shared__ __attribute__((aligned(16))) f16 sB [128 * 32];
  __shared__ __attribute__((aligned(16))) f16 sAl[SPLIT ? 128 * 32 : 8];
  __shared__ __attribute__((aligned(16))) f16 sT [OUTMODE == 2 ? 4 * 64 * 72 : 8];

  const int tid  = threadIdx.x;
  const int lane = tid & 63;
  const int wv   = tid >> 6;
  const int wr   = (wv >> 1) * 64;
  const int wc   = (wv & 1) * 64;
  const int brow = blockIdx.y * 128;
  const int bcol = blockIdx.x * 128;
  const int srow = tid >> 2;          // 0..63
  const int scol = (tid & 3) * 8;     // 0,8,16,24
  const int fr   = lane & 15;
  const int fq   = lane >> 4;
  const int fko  = fq * 8;

  f32x4 acc[4][4] = {};

  const int nk = K >> 5;
  for (int kt = 0; kt < nk; ++kt) {
    const int k0 = kt * 32;
    f16x8 ga0 = *(const f16x8*)(Ah + (long)(brow + srow) * K + k0 + scol);
    f16x8 ga1 = *(const f16x8*)(Ah + (long)(brow + 64 + srow) * K + k0 + scol);
    f16x8 gb0 = *(const f16x8*)(B  + (long)(bcol + srow) * K + k0 + scol);
    f16x8 gb1 = *(const f16x8*)(B  + (long)(bcol + 64 + srow) * K + k0 + scol);
    f16x8 gl0, gl1;
    if constexpr (SPLIT) {
      gl0 = *(const f16x8*)(Al + (long)(brow + srow) * K + k0 + scol);
      gl1 = *(const f16x8*)(Al + (long)(brow + 64 + srow) * K + k0 + scol);
    }
    __syncthreads();
    *(f16x8*)(sAh + srow * 32 + scol)        = ga0;
    *(f16x8*)(sAh + (64 + srow) * 32 + scol) = ga1;
    *(f16x8*)(sB  + srow * 32 + scol)        = gb0;
    *(f16x8*)(sB  + (64 + srow) * 32 + scol) = gb1;
    if constexpr (SPLIT) {
      *(f16x8*)(sAl + srow * 32 + scol)        = gl0;
      *(f16x8*)(sAl + (64 + srow) * 32 + scol) = gl1;
    }
    __syncthreads();

    f16x8 bfr[4];
    #pragma unroll
    for (int ni = 0; ni < 4; ++ni)
      bfr[ni] = *(const f16x8*)(sB + (wc + ni * 16 + fr) * 32 + fko);
    #pragma unroll
    for (int mi = 0; mi < 4; ++mi) {
      f16x8 ah = *(const f16x8*)(sAh + (wr + mi * 16 + fr) * 32 + fko);
      #pragma unroll
      for (int ni = 0; ni < 4; ++ni)
        acc[mi][ni] = mfma16(ah, bfr[ni], acc[mi][ni]);
      if constexpr (SPLIT) {
        f16x8 al = *(const f16x8*)(sAl + (wr + mi * 16 + fr) * 32 + fko);
        #pragma unroll
        for (int ni = 0; ni < 4; ++ni)
          acc[mi][ni] = mfma16(al, bfr[ni], acc[mi][ni]);
      }
    }
  }

  if constexpr (OUTMODE == 0) {
    #pragma unroll
    for (int mi = 0; mi < 4; ++mi)
      #pragma unroll
      for (int ni = 0; ni < 4; ++ni)
        #pragma unroll
        for (int r = 0; r < 4; ++r)
          C[(long)(brow + wr + mi * 16 + fq * 4 + r) * N + (bcol + wc + ni * 16 + fr)]
              = acc[mi][ni][r];
  } else if constexpr (OUTMODE == 1) {
    #pragma unroll
    for (int mi = 0; mi < 4; ++mi)
      #pragma unroll
      for (int ni = 0; ni < 4; ++ni)
        #pragma unroll
        for (int r = 0; r < 4; ++r) {
          long idx = (long)(brow + wr + mi * 16 + fq * 4 + r) * N
                   + (bcol + wc + ni * 16 + fr);
          float v = acc[mi][ni][r];
          f16 hv = (f16)v;
          O1[idx] = hv;
          O2[idx] = (f16)(v - (float)hv);
        }
  } else {  // OUTMODE == 2
    const int colbase = bcol + wc;     // multiple of 64, block-uniform K/V split
    if (colbase < 512) {
      #pragma unroll
      for (int mi = 0; mi < 4; ++mi)
        #pragma unroll
        for (int ni = 0; ni < 4; ++ni)
          #pragma unroll
          for (int r = 0; r < 4; ++r) {
            long idx = (long)(brow + wr + mi * 16 + fq * 4 + r) * KVW_
                     + colbase + ni * 16 + fr;
            float v = acc[mi][ni][r];
            f16 hv = (f16)v;
            O1[idx] = hv;
            O2[idx] = (f16)(v - (float)hv);
          }
    } else {
      const int khh = (colbase - 512) >> 6;   // kv head 0..7
      const int bb  = brow >> 11;             // batch (SEQ=2048, brow mult of 128)
      const int s0  = (brow & (SEQ_ - 1)) + wr;
      f16* st = sT + wv * 64 * 72;            // per-wave [d=64][s=64] pad 72
      #pragma unroll
      for (int mi = 0; mi < 4; ++mi)
        #pragma unroll
        for (int ni = 0; ni < 4; ++ni)
          #pragma unroll
          for (int r = 0; r < 4; ++r)
            st[(ni * 16 + fr) * 72 + mi * 16 + fq * 4 + r] = (f16)acc[mi][ni][r];
      __syncthreads();
      #pragma unroll
      for (int i = 0; i < 8; ++i) {
        int d  = i * 8 + (lane >> 3);
        int sc = (lane & 7) * 8;
        f16x8 v = *(const f16x8*)(st + d * 72 + sc);
        *(f16x8*)(OV + ((long)(bb * 8 + khh) * 64 + d) * SEQ_ + s0 + sc) = v;
      }
    }
  }
}

// ---------------- flash attention (causal, GQA 4:1) ----------------
// grid (pair=16, h=32, b=2): each block does q-tiles {p, 31-p} => 33 kv-iters,
// perfectly balanced, 1024 blocks = 4/CU.  256 threads = 4 waves x 16 q-rows.
// K pre-split f16 hi/lo; V pre-transposed f16 [b][kh][d][s].  Single-buffered
// LDS tiles (32KB) with register prefetch of the next kv tile.
__global__ __launch_bounds__(256)
void attn_kernel(const f16* __restrict__ qhi, const f16* __restrict__ qlo,
                 const f16* __restrict__ khi, const f16* __restrict__ klo,
                 const f16* __restrict__ vt,  f16* __restrict__ AO) {
  const int p    = blockIdx.x;
  const int h    = blockIdx.y;
  const int b    = blockIdx.z;
  const int kh   = h >> 2;
  const int tid  = threadIdx.x;
  const int lane = tid & 63;
  const int w    = tid >> 6;
  const int fr   = lane & 15;
  const int fq   = lane >> 4;

  // linear [64 rows][128B] tiles, XOR-swizzled at 16B granularity
  __shared__ __attribute__((aligned(16))) char sKh[64 * 128];
  __shared__ __attribute__((aligned(16))) char sKl[64 * 128];
  __shared__ __attribute__((aligned(16))) char sVt[64 * 128];
  __shared__ __attribute__((aligned(16))) char sP [4][16 * 128];

  const int srow = w * 16 + (lane >> 3);      // staging row (+0 / +8)
  const int sxor = (lane >> 3) << 4;          // (row&7)<<4 for staging rows
  const int scb  = (lane & 7) * 16;           // staging chunk byte
  const int kcol = kh * HD_ + (lane & 7) * 8; // f16 col in khi/klo
  const int qxr  = (fr & 7) << 4;             // (row&7)<<4 for fragment rows
  char* pw = sP[w];

  f16x8 rkh[2], rkl[2], rvt[2];
  auto loadKV = [&](int kb) {
    const long kr = (long)(b * SEQ_ + kb * 64 + srow);
    rkh[0] = *(const f16x8*)(khi + kr * KVW_ + kcol);
    rkh[1] = *(const f16x8*)(khi + (kr + 8) * KVW_ + kcol);
    rkl[0] = *(const f16x8*)(klo + kr * KVW_ + kcol);
    rkl[1] = *(const f16x8*)(klo + (kr + 8) * KVW_ + kcol);
    const f16* vb = vt + ((long)(b * 8 + kh) * 64 + srow) * SEQ_ + kb * 64 + (lane & 7) * 8;
    rvt[0] = *(const f16x8*)(vb);
    rvt[1] = *(const f16x8*)(vb + 8 * SEQ_);
  };
  auto stage = [&]() {
    const int cb = scb ^ sxor;
    const int rb0 = srow * 128, rb1 = rb0 + 8 * 128;
    *(f16x8*)(sKh + rb0 + cb) = rkh[0];
    *(f16x8*)(sKh + rb1 + cb) = rkh[1];
    *(f16x8*)(sKl + rb0 + cb) = rkl[0];
    *(f16x8*)(sKl + rb1 + cb) = rkl[1];
    *(f16x8*)(sVt + rb0 + cb) = rvt[0];
    *(f16x8*)(sVt + rb1 + cb) = rvt[1];
  };

  #pragma unroll 1
  for (int pass = 0; pass < 2; ++pass) {
    const int qblk  = pass ? (31 - p) : p;
    const int qrow0 = qblk * 64 + w * 16;

    f16x8 qh[2], ql[2];
    {
      const long qoff = (long)(b * SEQ_ + qrow0 + fr) * DIM_ + h * HD_;
      qh[0] = *(const f16x8*)(qhi + qoff + fq * 8);
      qh[1] = *(const f16x8*)(qhi + qoff + 32 + fq * 8);
      ql[0] = *(const f16x8*)(qlo + qoff + fq * 8);
      ql[1] = *(const f16x8*)(qlo + qoff + 32 + fq * 8);
    }

    float m_run[4], l_run[4];
    #pragma unroll
    for (int r = 0; r < 4; ++r) { m_run[r] = -1e30f; l_run[r] = 0.f; }
    f32x4 o_acc[4] = {};

    loadKV(0);
    #pragma unroll 1
    for (int kb = 0; kb <= qblk; ++kb) {
      stage();
      __syncthreads();
      if (kb < qblk) loadKV(kb + 1);   // prefetch next tile under compute

      // S = Q K^T (hi/lo split: qh*kh + ql*kh + qh*kl)
      f32x4 s[4] = {};
      #pragma unroll
      for (int ks = 0; ks < 2; ++ks) {
        const int cb = (ks * 64 + fq * 16) ^ qxr;
        #pragma unroll
        for (int ni = 0; ni < 4; ++ni) {
          const int rb = (ni * 16 + fr) * 128;
          f16x8 khf = *(const f16x8*)(sKh + rb + cb);
          f16x8 klf = *(const f16x8*)(sKl + rb + cb);
          s[ni] = mfma16(qh[ks], khf, s[ni]);
          s[ni] = mfma16(ql[ks], khf, s[ni]);
          s[ni] = mfma16(qh[ks], klf, s[ni]);
        }
      }
      float sv[4][4];
      #pragma unroll
      for (int ni = 0; ni < 4; ++ni)
        #pragma unroll
        for (int r = 0; r < 4; ++r)
          sv[ni][r] = s[ni][r] * 0.125f;
      if (kb == qblk) {
        #pragma unroll
        for (int ni = 0; ni < 4; ++ni) {
          int kvp = ni * 16 + fr;
          #pragma unroll
          for (int r = 0; r < 4; ++r)
            if (kvp > w * 16 + fq * 4 + r) sv[ni][r] = -1e30f;
        }
      }
      // online softmax per q-row (row r lives in the 16-lane group fq)
      #pragma unroll
      for (int r = 0; r < 4; ++r) {
        float mb = fmaxf(fmaxf(sv[0][r], sv[1][r]), fmaxf(sv[2][r], sv[3][r]));
        #pragma unroll
        for (int off = 8; off > 0; off >>= 1)
          mb = fmaxf(mb, __shfl_xor(mb, off, 16));
        float mn = fmaxf(m_run[r], mb);
        float al = __expf(m_run[r] - mn);
        m_run[r] = mn;
        l_run[r] *= al;
        #pragma unroll
        for (int di = 0; di < 4; ++di) o_acc[di][r] *= al;
        float rs = 0.f;
        const int prxor = ((fq * 4 + r) & 7) << 4;
        #pragma unroll
        for (int ni = 0; ni < 4; ++ni) {
          float pv = __expf(sv[ni][r] - mn);
          rs += pv;
          *(f16*)(pw + (fq * 4 + r) * 128 + ((ni * 32 + fr * 2) ^ prxor)) = (f16)pv;
        }
        #pragma unroll
        for (int off = 8; off > 0; off >>= 1)
          rs += __shfl_xor(rs, off, 16);
        l_run[r] += rs;
      }
      // O += P V   (A = P[16 x 64], B = Vt rows d with kv contiguous)
      #pragma unroll
      for (int ks = 0; ks < 2; ++ks) {
        const int cb = (ks * 64 + fq * 16) ^ qxr;
        f16x8 pa = *(const f16x8*)(pw + fr * 128 + cb);
        #pragma unroll
        for (int di = 0; di < 4; ++di) {
          f16x8 vtf = *(const f16x8*)(sVt + (di * 16 + fr) * 128 + cb);
          o_acc[di] = mfma16(pa, vtf, o_acc[di]);
        }
      }
      __syncthreads();
    }

    #pragma unroll
    for (int di = 0; di < 4; ++di)
      #pragma unroll
      for (int r = 0; r < 4; ++r) {
        float val = o_acc[di][r] / l_run[r];
        AO[(long)(b * SEQ_ + qrow0 + fq * 4 + r) * DIM_ + h * HD_ + di * 16 + fr] = (f16)val;
      }
  }
}

// ---------------- launch ----------------
extern "C" void kernel_launch(void* const* d_in, const int* in_sizes, int n_in,
                              void* d_out, int out_size, void* d_ws, size_t ws_size,
                              hipStream_t stream) {
  const float* x  = (const float*)d_in[0];
  const float* wq = (const float*)d_in[1];
  const float* wk = (const float*)d_in[2];
  const float* wv = (const float*)d_in[3];
  const float* wo = (const float*)d_in[4];
  char* ws = (char*)d_ws;

  size_t off = 0;
  float* sums = (float*)ws;                 off = 256;
  f16* x_hi  = (f16*)(ws + off);            off += (size_t)MROWS_ * DIM_ * 2;
  f16* x_lo  = (f16*)(ws + off);            off += (size_t)MROWS_ * DIM_ * 2;
  f16* wq_t  = (f16*)(ws + off);            off += (size_t)DIM_ * DIM_ * 2;
  f16* wkv_t = (f16*)(ws + off);            off += (size_t)1024 * DIM_ * 2;
  f16* wo_t  = (f16*)(ws + off);            off += (size_t)DIM_ * DIM_ * 2;
  f16* qhi   = (f16*)(ws + off);            off += (size_t)MROWS_ * DIM_ * 2;
  f16* qlo   = (f16*)(ws + off);            off += (size_t)MROWS_ * DIM_ * 2;
  f16* khi   = (f16*)(ws + off);            off += (size_t)MROWS_ * KVW_ * 2;
  f16* klo   = (f16*)(ws + off);            off += (size_t)MROWS_ * KVW_ * 2;
  f16* vtb   = (f16*)(ws + off);            off += (size_t)BATCH_ * 8 * 64 * SEQ_ * 2;
  f16* ao    = (f16*)(ws + off);            off += (size_t)MROWS_ * DIM_ * 2;

  hipMemsetAsync(sums, 0, 256, stream);  // atomics must start at 0 on every replay

  abssum_kernel<<<dim3(512), dim3(256), 0, stream>>>(wq, DIM_ * DIM_, sums + 0);
  abssum_kernel<<<dim3(256), dim3(256), 0, stream>>>(wk, 512 * DIM_, sums + 1);
  abssum_kernel<<<dim3(256), dim3(256), 0, stream>>>(wv, 512 * DIM_, sums + 2);
  abssum_kernel<<<dim3(512), dim3(256), 0, stream>>>(wo, DIM_ * DIM_, sums + 3);

  ternarize_kernel<<<dim3(512), dim3(256), 0, stream>>>(
      wq, DIM_ * DIM_ / 4, sums + 0, 1.f / (float)(DIM_ * DIM_), (unsigned short*)wq_t);
  ternarize_kernel<<<dim3(256), dim3(256), 0, stream>>>(
      wk, 512 * DIM_ / 4, sums + 1, 1.f / (float)(512 * DIM_), (unsigned short*)wkv_t);
  ternarize_kernel<<<dim3(256), dim3(256), 0, stream>>>(
      wv, 512 * DIM_ / 4, sums + 2, 1.f / (float)(512 * DIM_),
      (unsigned short*)(wkv_t + (size_t)512 * DIM_));
  ternarize_kernel<<<dim3(512), dim3(256), 0, stream>>>(
      wo, DIM_ * DIM_ / 4, sums + 3, 1.f / (float)(DIM_ * DIM_), (unsigned short*)wo_t);

  splitx_kernel<<<dim3(1024), dim3(256), 0, stream>>>(x, MROWS_ * DIM_ / 4, x_hi, x_lo);

  // q projection -> f16 hi/lo directly
  gemm_nt<true, 1><<<dim3(DIM_ / 128, MROWS_ / 128), dim3(256), 0, stream>>>(
      x_hi, x_lo, wq_t, nullptr, qhi, qlo, nullptr, MROWS_, DIM_, DIM_);
  // kv projection -> khi/klo + transposed V
  gemm_nt<true, 2><<<dim3(1024 / 128, MROWS_ / 128), dim3(256), 0, stream>>>(
      x_hi, x_lo, wkv_t, nullptr, khi, klo, vtb, MROWS_, 1024, DIM_);

  attn_kernel<<<dim3(16, 32, BATCH_), dim3(256), 0, stream>>>(qhi, qlo, khi, klo, vtb, ao);

  gemm_nt<false, 0><<<dim3(DIM_ / 128, MROWS_ / 128), dim3(256), 0, stream>>>(
      ao, ao, wo_t, (float*)d_out, nullptr, nullptr, nullptr, MROWS_, DIM_, DIM_);
}

// Round 3
// 369.751 us; speedup vs baseline: 1.8076x; 1.2205x over previous
//
#include <hip/hip_runtime.h>

typedef _Float16 f16;
typedef f16  f16x8 __attribute__((ext_vector_type(8)));
typedef f16  f16x4 __attribute__((ext_vector_type(4)));
typedef float f32x4 __attribute__((ext_vector_type(4)));

#define DIM_   2048
#define SEQ_   2048
#define BATCH_ 2
#define MROWS_ (BATCH_*SEQ_)   // 4096
#define HD_    64
#define KVW_   512             // k (or v) projection width

__device__ __forceinline__ f32x4 mfma16(f16x8 a, f16x8 b, f32x4 c) {
  return __builtin_amdgcn_mfma_f32_16x16x32_f16(a, b, c, 0, 0, 0);
}

// async global->LDS, 16B per lane; LDS dest is wave-uniform base + lane*16
typedef const __attribute__((address_space(1))) void gas_void;
typedef __attribute__((address_space(3))) void las_void;
__device__ __forceinline__ void gload16(const void* g, void* l) {
  __builtin_amdgcn_global_load_lds((gas_void*)g, (las_void*)l, 16, 0, 0);
}

// DPP row_ror reductions over a 16-lane row (no LDS pipe, unlike ds_swizzle)
template<int C>
__device__ __forceinline__ float dmax(float x) {
  return fmaxf(x, __int_as_float(__builtin_amdgcn_update_dpp(
      0, __float_as_int(x), C, 0xF, 0xF, false)));
}
template<int C>
__device__ __forceinline__ float dsum(float x) {
  return x + __int_as_float(__builtin_amdgcn_update_dpp(
      0, __float_as_int(x), C, 0xF, 0xF, false));
}

// ---------------- fused |w| sums (one launch, 4 weights) ----------------
__global__ __launch_bounds__(256)
void abssum4(const float* __restrict__ w0, const float* __restrict__ w1,
             const float* __restrict__ w2, const float* __restrict__ w3,
             float* __restrict__ sums) {
  const int id = blockIdx.y;
  const float* w = id == 0 ? w0 : id == 1 ? w1 : id == 2 ? w2 : w3;
  const int n4 = (id == 1 || id == 2) ? (KVW_ * DIM_ / 4) : (DIM_ * DIM_ / 4);
  float s = 0.f;
  for (int i = blockIdx.x * 256 + threadIdx.x; i < n4; i += gridDim.x * 256) {
    float4 v = *(const float4*)(w + (long)i * 4);
    s += fabsf(v.x) + fabsf(v.y) + fabsf(v.z) + fabsf(v.w);
  }
  #pragma unroll
  for (int off = 32; off > 0; off >>= 1)
    s += __shfl_down(s, off, 64);
  __shared__ float red[4];
  int lane = threadIdx.x & 63, wv = threadIdx.x >> 6;
  if (lane == 0) red[wv] = s;
  __syncthreads();
  if (threadIdx.x == 0)
    atomicAdd(sums + id, red[0] + red[1] + red[2] + red[3]);
}

// ---------------- fused ternarize (one launch, 4 weights) ----------------
__global__ __launch_bounds__(256)
void ternarize4(const float* __restrict__ w0, const float* __restrict__ w1,
                const float* __restrict__ w2, const float* __restrict__ w3,
                unsigned short* __restrict__ t0, unsigned short* __restrict__ t1,
                unsigned short* __restrict__ t2, unsigned short* __restrict__ t3,
                const float* __restrict__ sums) {
  const int id = blockIdx.y;
  const float* w = id == 0 ? w0 : id == 1 ? w1 : id == 2 ? w2 : w3;
  unsigned short* t = id == 0 ? t0 : id == 1 ? t1 : id == 2 ? t2 : t3;
  const int n = (id == 1 || id == 2) ? (KVW_ * DIM_) : (DIM_ * DIM_);
  const float thr = 0.05f * fmaxf(sums[id] / (float)n, 1e-6f);
  const int n4 = n >> 2;
  for (int i = blockIdx.x * 256 + threadIdx.x; i < n4; i += gridDim.x * 256) {
    float4 v = *(const float4*)(w + (long)i * 4);
    ushort4 o;
    o.x = v.x > thr ? 0x3C00 : (v.x < -thr ? 0xBC00 : 0);
    o.y = v.y > thr ? 0x3C00 : (v.y < -thr ? 0xBC00 : 0);
    o.z = v.z > thr ? 0x3C00 : (v.z < -thr ? 0xBC00 : 0);
    o.w = v.w > thr ? 0x3C00 : (v.w < -thr ? 0xBC00 : 0);
    *(ushort4*)(t + (long)i * 4) = o;
  }
}

// ---------------- split x into fp16 hi + lo ----------------
__global__ __launch_bounds__(256)
void splitx_kernel(const float* __restrict__ x, int n4,
                   f16* __restrict__ hi, f16* __restrict__ lo) {
  int stride = gridDim.x * 256;
  for (int i = blockIdx.x * 256 + threadIdx.x; i < n4; i += stride) {
    float4 v = *(const float4*)(x + (long)i * 4);
    f16x4 h, l;
    h[0] = (f16)v.x; l[0] = (f16)(v.x - (float)h[0]);
    h[1] = (f16)v.y; l[1] = (f16)(v.y - (float)h[1]);
    h[2] = (f16)v.z; l[2] = (f16)(v.z - (float)h[2]);
    h[3] = (f16)v.w; l[3] = (f16)(v.w - (float)h[3]);
    *(f16x4*)(hi + (long)i * 4) = h;
    *(f16x4*)(lo + (long)i * 4) = l;
  }
}

// ---------------- NT GEMM via global_load_lds (m97 structure) ----------------
// 128x128 tile, BK=32, 256 threads (4 waves, each a 64x64 sub-tile of 4x4 frags).
// OUTMODE 0: f32 C.   OUTMODE 3: combined qkv epilogue by output column:
//   col <2048 -> q hi/lo (O1,O2); <2560 -> k hi/lo (K1,K2);
//   >=2560 -> V transposed f16 into OV [b][kvh][d=64][s=2048].
template<bool SPLIT, int OUTMODE>
__global__ __launch_bounds__(256)
void gemm_nt(const f16* __restrict__ Ah, const f16* __restrict__ Al,
             const f16* __restrict__ B, float* __restrict__ C,
             f16* __restrict__ O1, f16* __restrict__ O2,
             f16* __restrict__ K1, f16* __restrict__ K2,
             f16* __restrict__ OV, int M, int N, int K) {
  __shared__ __attribute__((aligned(16))) f16 sAh[128 * 32];
  __shared__ __attribute__((aligned(16))) f16 sB [128 * 32];
  __shared__ __attribute__((aligned(16))) f16 sAl[SPLIT ? 128 * 32 : 8];
  __shared__ __attribute__((aligned(16))) f16 sT [OUTMODE == 3 ? 4 * 32 * 72 : 8];

  const int tid  = threadIdx.x;
  const int lane = tid & 63;
  const int wv   = tid >> 6;
  const int wr   = (wv >> 1) * 64;
  const int wc   = (wv & 1) * 64;
  const int brow = blockIdx.y * 128;
  const int bcol = blockIdx.x * 128;
  const int fr   = lane & 15;
  const int fq   = lane >> 4;
  const int fko  = fq * 8;

  // staging: wave wv covers tile rows [wv*32, wv*32+32); lane -> (row, 16B chunk)
  const int srow = wv * 32 + (lane >> 2);
  const int scol = (lane & 3) * 8;
  const f16* gA0 = Ah + (long)(brow + srow) * K + scol;
  const f16* gA1 = gA0 + 16 * (long)K;
  const f16* gB0 = B + (long)(bcol + srow) * K + scol;
  const f16* gB1 = gB0 + 16 * (long)K;
  const f16* gL0 = SPLIT ? (Al + (long)(brow + srow) * K + scol) : nullptr;
  const f16* gL1 = SPLIT ? (gL0 + 16 * (long)K) : nullptr;
  const int lb = __builtin_amdgcn_readfirstlane(wv * 32 * 32);
  f16* lA0 = sAh + lb;  f16* lA1 = lA0 + 16 * 32;
  f16* lB0 = sB  + lb;  f16* lB1 = lB0 + 16 * 32;
  f16* lL0 = sAl + lb;  f16* lL1 = lL0 + 16 * 32;

  f32x4 acc[4][4] = {};

  #pragma unroll 1
  for (int k0 = 0; k0 < K; k0 += 32) {
    gload16(gA0 + k0, lA0);
    gload16(gA1 + k0, lA1);
    gload16(gB0 + k0, lB0);
    gload16(gB1 + k0, lB1);
    if constexpr (SPLIT) {
      gload16(gL0 + k0, lL0);
      gload16(gL1 + k0, lL1);
    }
    __syncthreads();   // vmcnt(0) drain + barrier: LDS tile ready

    f16x8 bfr[4];
    #pragma unroll
    for (int ni = 0; ni < 4; ++ni)
      bfr[ni] = *(const f16x8*)(sB + (wc + ni * 16 + fr) * 32 + fko);
    #pragma unroll
    for (int mi = 0; mi < 4; ++mi) {
      f16x8 ah = *(const f16x8*)(sAh + (wr + mi * 16 + fr) * 32 + fko);
      #pragma unroll
      for (int ni = 0; ni < 4; ++ni)
        acc[mi][ni] = mfma16(ah, bfr[ni], acc[mi][ni]);
      if constexpr (SPLIT) {
        f16x8 al = *(const f16x8*)(sAl + (wr + mi * 16 + fr) * 32 + fko);
        #pragma unroll
        for (int ni = 0; ni < 4; ++ni)
          acc[mi][ni] = mfma16(al, bfr[ni], acc[mi][ni]);
      }
    }
    __syncthreads();   // all waves done reading before next stage overwrites
  }

  if constexpr (OUTMODE == 0) {
    #pragma unroll
    for (int mi = 0; mi < 4; ++mi)
      #pragma unroll
      for (int ni = 0; ni < 4; ++ni)
        #pragma unroll
        for (int r = 0; r < 4; ++r)
          C[(long)(brow + wr + mi * 16 + fq * 4 + r) * N + (bcol + wc + ni * 16 + fr)]
              = acc[mi][ni][r];
  } else {  // OUTMODE == 3
    const int colbase = bcol + wc;   // 64-aligned; regions are 128-aligned
    if (colbase < 2048) {            // q -> hi/lo, stride DIM_
      #pragma unroll
      for (int mi = 0; mi < 4; ++mi)
        #pragma unroll
        for (int ni = 0; ni < 4; ++ni)
          #pragma unroll
          for (int r = 0; r < 4; ++r) {
            long idx = (long)(brow + wr + mi * 16 + fq * 4 + r) * DIM_
                     + colbase + ni * 16 + fr;
            float v = acc[mi][ni][r];
            f16 hv = (f16)v;
            O1[idx] = hv;
            O2[idx] = (f16)(v - (float)hv);
          }
    } else if (colbase < 2560) {     // k -> hi/lo, stride KVW_
      #pragma unroll
      for (int mi = 0; mi < 4; ++mi)
        #pragma unroll
        for (int ni = 0; ni < 4; ++ni)
          #pragma unroll
          for (int r = 0; r < 4; ++r) {
            long idx = (long)(brow + wr + mi * 16 + fq * 4 + r) * KVW_
                     + (colbase - 2048) + ni * 16 + fr;
            float v = acc[mi][ni][r];
            f16 hv = (f16)v;
            K1[idx] = hv;
            K2[idx] = (f16)(v - (float)hv);
          }
    } else {                         // v -> transpose to [b][kvh][d][s]
      const int khh = (colbase - 2560) >> 6;   // kv head 0..7
      const int bb  = brow >> 11;              // batch
      const int s0  = (brow & (SEQ_ - 1)) + wr;
      f16* st = sT + wv * 32 * 72;             // per-wave [32 d][64 s] pad 72
      #pragma unroll
      for (int nh = 0; nh < 2; ++nh) {         // two d-halves of 32
        #pragma unroll
        for (int nj = 0; nj < 2; ++nj) {
          const int ni = nh * 2 + nj;
          #pragma unroll
          for (int mi = 0; mi < 4; ++mi)
            #pragma unroll
            for (int r = 0; r < 4; ++r)
              st[(nj * 16 + fr) * 72 + mi * 16 + fq * 4 + r] = (f16)acc[mi][ni][r];
        }
        // wave-local write->read; compiler inserts lgkmcnt waits
        #pragma unroll
        for (int i = 0; i < 4; ++i) {
          int dl = i * 8 + (lane >> 3);
          f16x8 v = *(const f16x8*)(st + dl * 72 + (lane & 7) * 8);
          *(f16x8*)(OV + ((long)(bb * 8 + khh) * 64 + nh * 32 + dl) * SEQ_
                    + s0 + (lane & 7) * 8) = v;
        }
      }
    }
  }
}

// ---------------- flash attention (causal, GQA 4:1) ----------------
// grid (pair=16, h=32, b=2): block does q-tiles {p, 31-p} => 33 kv-iters.
// 256 threads = 4 waves x 16 q-rows. K pre-split f16 hi/lo; V pre-transposed.
// Softmax: raw scores, DPP row_ror reductions, defer-max (skip rescale while
// tile max <= running max + 64 raw units i.e. P <= e^8).
__global__ __launch_bounds__(256)
void attn_kernel(const f16* __restrict__ qhi, const f16* __restrict__ qlo,
                 const f16* __restrict__ khi, const f16* __restrict__ klo,
                 const f16* __restrict__ vt,  f16* __restrict__ AO) {
  const int p    = blockIdx.x;
  const int h    = blockIdx.y;
  const int b    = blockIdx.z;
  const int kh   = h >> 2;
  const int tid  = threadIdx.x;
  const int lane = tid & 63;
  const int w    = tid >> 6;
  const int fr   = lane & 15;
  const int fq   = lane >> 4;

  // linear [64 rows][128B] tiles, XOR-swizzled at 16B granularity
  __shared__ __attribute__((aligned(16))) char sKh[64 * 128];
  __shared__ __attribute__((aligned(16))) char sKl[64 * 128];
  __shared__ __attribute__((aligned(16))) char sVt[64 * 128];
  __shared__ __attribute__((aligned(16))) char sP [4][16 * 128];

  const int srow = w * 16 + (lane >> 3);      // staging row (+0 / +8)
  const int sxor = (lane >> 3) << 4;          // (row&7)<<4 for staging rows
  const int scb  = (lane & 7) * 16;           // staging chunk byte
  const int kcol = kh * HD_ + (lane & 7) * 8; // f16 col in khi/klo
  const int qxr  = (fr & 7) << 4;             // (row&7)<<4 for fragment rows
  char* pw = sP[w];

  f16x8 rkh[2], rkl[2], rvt[2];
  auto loadKV = [&](int kb) {
    const long kr = (long)(b * SEQ_ + kb * 64 + srow);
    rkh[0] = *(const f16x8*)(khi + kr * KVW_ + kcol);
    rkh[1] = *(const f16x8*)(khi + (kr + 8) * KVW_ + kcol);
    rkl[0] = *(const f16x8*)(klo + kr * KVW_ + kcol);
    rkl[1] = *(const f16x8*)(klo + (kr + 8) * KVW_ + kcol);
    const f16* vb = vt + ((long)(b * 8 + kh) * 64 + srow) * SEQ_ + kb * 64 + (lane & 7) * 8;
    rvt[0] = *(const f16x8*)(vb);
    rvt[1] = *(const f16x8*)(vb + 8 * SEQ_);
  };
  auto stage = [&]() {
    const int cb = scb ^ sxor;
    const int rb0 = srow * 128, rb1 = rb0 + 8 * 128;
    *(f16x8*)(sKh + rb0 + cb) = rkh[0];
    *(f16x8*)(sKh + rb1 + cb) = rkh[1];
    *(f16x8*)(sKl + rb0 + cb) = rkl[0];
    *(f16x8*)(sKl + rb1 + cb) = rkl[1];
    *(f16x8*)(sVt + rb0 + cb) = rvt[0];
    *(f16x8*)(sVt + rb1 + cb) = rvt[1];
  };

  #pragma unroll 1
  for (int pass = 0; pass < 2; ++pass) {
    const int qblk  = pass ? (31 - p) : p;
    const int qrow0 = qblk * 64 + w * 16;

    f16x8 qh[2], ql[2];
    {
      const long qoff = (long)(b * SEQ_ + qrow0 + fr) * DIM_ + h * HD_;
      qh[0] = *(const f16x8*)(qhi + qoff + fq * 8);
      qh[1] = *(const f16x8*)(qhi + qoff + 32 + fq * 8);
      ql[0] = *(const f16x8*)(qlo + qoff + fq * 8);
      ql[1] = *(const f16x8*)(qlo + qoff + 32 + fq * 8);
    }

    float m_run[4], l_run[4];
    #pragma unroll
    for (int r = 0; r < 4; ++r) { m_run[r] = -1e30f; l_run[r] = 0.f; }
    f32x4 o_acc[4] = {};

    loadKV(0);
    #pragma unroll 1
    for (int kb = 0; kb <= qblk; ++kb) {
      stage();
      __syncthreads();
      if (kb < qblk) loadKV(kb + 1);   // prefetch next tile under compute

      // S = Q K^T raw (hi/lo split: qh*kh + ql*kh + qh*kl)
      f32x4 s[4] = {};
      #pragma unroll
      for (int ks = 0; ks < 2; ++ks) {
        const int cb = (ks * 64 + fq * 16) ^ qxr;
        #pragma unroll
        for (int ni = 0; ni < 4; ++ni) {
          const int rb = (ni * 16 + fr) * 128;
          f16x8 khf = *(const f16x8*)(sKh + rb + cb);
          f16x8 klf = *(const f16x8*)(sKl + rb + cb);
          s[ni] = mfma16(qh[ks], khf, s[ni]);
          s[ni] = mfma16(ql[ks], khf, s[ni]);
          s[ni] = mfma16(qh[ks], klf, s[ni]);
        }
      }
      if (kb == qblk) {
        #pragma unroll
        for (int ni = 0; ni < 4; ++ni) {
          int kvp = ni * 16 + fr;
          #pragma unroll
          for (int r = 0; r < 4; ++r)
            if (kvp > w * 16 + fq * 4 + r) s[ni][r] = -1e30f;
        }
      }
      // online softmax per q-row; scale 0.125 folded into exp argument
      #pragma unroll
      for (int r = 0; r < 4; ++r) {
        float mb = fmaxf(fmaxf(s[0][r], s[1][r]), fmaxf(s[2][r], s[3][r]));
        mb = dmax<0x121>(mb);  // ror:1
        mb = dmax<0x122>(mb);  // ror:2
        mb = dmax<0x124>(mb);  // ror:4
        mb = dmax<0x128>(mb);  // ror:8
        float mo = m_run[r], mn = mo;
        if (mb > mo + 64.0f) {           // defer-max: only rescale on real growth
          float al = __expf((mo - mb) * 0.125f);
          l_run[r] *= al;
          o_acc[0][r] *= al; o_acc[1][r] *= al;
          o_acc[2][r] *= al; o_acc[3][r] *= al;
          m_run[r] = mb; mn = mb;
        }
        float rs = 0.f;
        const int prxor = ((fq * 4 + r) & 7) << 4;
        #pragma unroll
        for (int ni = 0; ni < 4; ++ni) {
          float pv = __expf((s[ni][r] - mn) * 0.125f);
          rs += pv;
          *(f16*)(pw + (fq * 4 + r) * 128 + ((ni * 32 + fr * 2) ^ prxor)) = (f16)pv;
        }
        rs = dsum<0x121>(rs);
        rs = dsum<0x122>(rs);
        rs = dsum<0x124>(rs);
        rs = dsum<0x128>(rs);
        l_run[r] += rs;
      }
      // O += P V   (A = P[16 x 64], B = Vt rows d with kv contiguous)
      #pragma unroll
      for (int ks = 0; ks < 2; ++ks) {
        const int cb = (ks * 64 + fq * 16) ^ qxr;
        f16x8 pa = *(const f16x8*)(pw + fr * 128 + cb);
        #pragma unroll
        for (int di = 0; di < 4; ++di) {
          f16x8 vtf = *(const f16x8*)(sVt + (di * 16 + fr) * 128 + cb);
          o_acc[di] = mfma16(pa, vtf, o_acc[di]);
        }
      }
      __syncthreads();
    }

    #pragma unroll
    for (int di = 0; di < 4; ++di)
      #pragma unroll
      for (int r = 0; r < 4; ++r) {
        float val = o_acc[di][r] / l_run[r];
        AO[(long)(b * SEQ_ + qrow0 + fq * 4 + r) * DIM_ + h * HD_ + di * 16 + fr] = (f16)val;
      }
  }
}

// ---------------- launch ----------------
extern "C" void kernel_launch(void* const* d_in, const int* in_sizes, int n_in,
                              void* d_out, int out_size, void* d_ws, size_t ws_size,
                              hipStream_t stream) {
  const float* x  = (const float*)d_in[0];
  const float* wq = (const float*)d_in[1];
  const float* wk = (const float*)d_in[2];
  const float* wv = (const float*)d_in[3];
  const float* wo = (const float*)d_in[4];
  char* ws = (char*)d_ws;

  size_t off = 0;
  float* sums = (float*)ws;                 off = 256;
  f16* x_hi  = (f16*)(ws + off);            off += (size_t)MROWS_ * DIM_ * 2;
  f16* x_lo  = (f16*)(ws + off);            off += (size_t)MROWS_ * DIM_ * 2;
  f16* wq_t  = (f16*)(ws + off);            off += (size_t)DIM_ * DIM_ * 2;
  f16* wkv_t = (f16*)(ws + off);            off += (size_t)1024 * DIM_ * 2;  // contiguous after wq_t
  f16* wo_t  = (f16*)(ws + off);            off += (size_t)DIM_ * DIM_ * 2;
  f16* qhi   = (f16*)(ws + off);            off += (size_t)MROWS_ * DIM_ * 2;
  f16* qlo   = (f16*)(ws + off);            off += (size_t)MROWS_ * DIM_ * 2;
  f16* khi   = (f16*)(ws + off);            off += (size_t)MROWS_ * KVW_ * 2;
  f16* klo   = (f16*)(ws + off);            off += (size_t)MROWS_ * KVW_ * 2;
  f16* vtb   = (f16*)(ws + off);            off += (size_t)BATCH_ * 8 * 64 * SEQ_ * 2;
  f16* ao    = (f16*)(ws + off);            off += (size_t)MROWS_ * DIM_ * 2;

  hipMemsetAsync(sums, 0, 64, stream);  // atomics must start at 0 on every replay

  abssum4<<<dim3(192, 4), dim3(256), 0, stream>>>(wq, wk, wv, wo, sums);
  ternarize4<<<dim3(192, 4), dim3(256), 0, stream>>>(
      wq, wk, wv, wo,
      (unsigned short*)wq_t, (unsigned short*)wkv_t,
      (unsigned short*)(wkv_t + (size_t)KVW_ * DIM_), (unsigned short*)wo_t,
      sums);

  splitx_kernel<<<dim3(1024), dim3(256), 0, stream>>>(x, MROWS_ * DIM_ / 4, x_hi, x_lo);

  // fused q+k+v projection: B = [wq_t ; wk_t ; wv_t] = 3072 rows (contiguous in ws)
  gemm_nt<true, 3><<<dim3(3072 / 128, MROWS_ / 128), dim3(256), 0, stream>>>(
      x_hi, x_lo, wq_t, nullptr, qhi, qlo, khi, klo, vtb, MROWS_, 3072, DIM_);

  attn_kernel<<<dim3(16, 32, BATCH_), dim3(256), 0, stream>>>(qhi, qlo, khi, klo, vtb, ao);

  gemm_nt<false, 0><<<dim3(DIM_ / 128, MROWS_ / 128), dim3(256), 0, stream>>>(
      ao, ao, wo_t, (float*)d_out, nullptr, nullptr, nullptr, nullptr, nullptr,
      MROWS_, DIM_, DIM_);
}